// Round 2
// baseline (55.544 us; speedup 1.0000x reference)
//
#include <hip/hip_runtime.h>
#include <math.h>

// Problem constants (match reference)
#define DDIM   1024
#define BATCH  2048        // B; image_features has 2*B rows
#define MROWS  16384
#define TEMP_INV 10.0f     // 1/0.1
#define EPSN   1e-8f

// Launch geometry
#define NA_BLOCKS 256      // one block per CU
#define NA_THREADS 1024    // 16 waves/block -> 4096 waves, 4 rows/wave
#define NA_WAVES (NA_BLOCKS * (NA_THREADS / 64))   // 4096
#define ROWS_PER_WAVE (MROWS / NA_WAVES)           // 4
#define NC_BLOCKS 512
#define NC_THREADS 256     // 4 waves/block -> 2048 waves = B pairs

// ws layout in floats (total ~1.03 MB)
#define OFF_PART 0                          // NA_BLOCKS * DDIM partial s
#define OFF_S    (NA_BLOCKS * DDIM)         // DDIM final s
#define OFF_LP   (OFF_S + DDIM)             // NC_BLOCKS loss partials

__device__ __forceinline__ float wave_sum(float v) {
    v += __shfl_xor(v, 32);
    v += __shfl_xor(v, 16);
    v += __shfl_xor(v, 8);
    v += __shfl_xor(v, 4);
    v += __shfl_xor(v, 2);
    v += __shfl_xor(v, 1);
    return v;
}

__device__ __forceinline__ float softplus_stable(float d) {
    return fmaxf(d, 0.0f) + log1pf(expf(-fabsf(d)));
}

// Kernel A: s_partial[block][d] = sum over assigned rows of row/||row||
// 4096 waves, 4 rows each (fully unrolled, all 16 float4 loads independent).
__global__ __launch_bounds__(NA_THREADS, 4)
void mb_sum_kernel(const float* __restrict__ mb, float* __restrict__ ws) {
    __shared__ float sb[DDIM];
    const int tid = threadIdx.x;
    sb[tid] = 0.0f;                 // blockDim.x == DDIM
    __syncthreads();

    const int lane  = tid & 63;
    const int wave  = tid >> 6;
    const int gwave = blockIdx.x * (NA_THREADS / 64) + wave;

    float4 a0 = {0,0,0,0}, a1 = {0,0,0,0}, a2 = {0,0,0,0}, a3 = {0,0,0,0};

    // rows: gwave + k*NA_WAVES, k = 0..3  — process as two pairs for reg moderation
    #pragma unroll
    for (int g = 0; g < ROWS_PER_WAVE / 2; ++g) {
        const int rA = gwave + (2 * g + 0) * NA_WAVES;
        const int rB = gwave + (2 * g + 1) * NA_WAVES;
        const float4* pA = reinterpret_cast<const float4*>(mb + (size_t)rA * DDIM);
        const float4* pB = reinterpret_cast<const float4*>(mb + (size_t)rB * DDIM);

        float4 A0 = pA[lane], A1 = pA[64 + lane], A2 = pA[128 + lane], A3 = pA[192 + lane];
        float4 B0 = pB[lane], B1 = pB[64 + lane], B2 = pB[128 + lane], B3 = pB[192 + lane];

        float sA = A0.x*A0.x + A0.y*A0.y + A0.z*A0.z + A0.w*A0.w
                 + A1.x*A1.x + A1.y*A1.y + A1.z*A1.z + A1.w*A1.w
                 + A2.x*A2.x + A2.y*A2.y + A2.z*A2.z + A2.w*A2.w
                 + A3.x*A3.x + A3.y*A3.y + A3.z*A3.z + A3.w*A3.w;
        float sB = B0.x*B0.x + B0.y*B0.y + B0.z*B0.z + B0.w*B0.w
                 + B1.x*B1.x + B1.y*B1.y + B1.z*B1.z + B1.w*B1.w
                 + B2.x*B2.x + B2.y*B2.y + B2.z*B2.z + B2.w*B2.w
                 + B3.x*B3.x + B3.y*B3.y + B3.z*B3.z + B3.w*B3.w;

        // two independent shfl-reduce chains — they interleave
        #pragma unroll
        for (int sh = 32; sh >= 1; sh >>= 1) {
            sA += __shfl_xor(sA, sh);
            sB += __shfl_xor(sB, sh);
        }
        float iA = 1.0f / fmaxf(sqrtf(sA), EPSN);
        float iB = 1.0f / fmaxf(sqrtf(sB), EPSN);

        a0.x += A0.x*iA + B0.x*iB; a0.y += A0.y*iA + B0.y*iB;
        a0.z += A0.z*iA + B0.z*iB; a0.w += A0.w*iA + B0.w*iB;
        a1.x += A1.x*iA + B1.x*iB; a1.y += A1.y*iA + B1.y*iB;
        a1.z += A1.z*iA + B1.z*iB; a1.w += A1.w*iA + B1.w*iB;
        a2.x += A2.x*iA + B2.x*iB; a2.y += A2.y*iA + B2.y*iB;
        a2.z += A2.z*iA + B2.z*iB; a2.w += A2.w*iA + B2.w*iB;
        a3.x += A3.x*iA + B3.x*iB; a3.y += A3.y*iA + B3.y*iB;
        a3.z += A3.z*iA + B3.z*iB; a3.w += A3.w*iA + B3.w*iB;
    }

    // 16 waves accumulate into block-local s via LDS atomics (16-way max).
    const int b = lane * 4;
    atomicAdd(&sb[b + 0],        a0.x); atomicAdd(&sb[b + 1],        a0.y);
    atomicAdd(&sb[b + 2],        a0.z); atomicAdd(&sb[b + 3],        a0.w);
    atomicAdd(&sb[256 + b + 0],  a1.x); atomicAdd(&sb[256 + b + 1],  a1.y);
    atomicAdd(&sb[256 + b + 2],  a1.z); atomicAdd(&sb[256 + b + 3],  a1.w);
    atomicAdd(&sb[512 + b + 0],  a2.x); atomicAdd(&sb[512 + b + 1],  a2.y);
    atomicAdd(&sb[512 + b + 2],  a2.z); atomicAdd(&sb[512 + b + 3],  a2.w);
    atomicAdd(&sb[768 + b + 0],  a3.x); atomicAdd(&sb[768 + b + 1],  a3.y);
    atomicAdd(&sb[768 + b + 2],  a3.z); atomicAdd(&sb[768 + b + 3],  a3.w);
    __syncthreads();

    ws[OFF_PART + (size_t)blockIdx.x * DDIM + tid] = sb[tid];
}

// Kernel B: s[d] = sum over blocks of s_partial[block][d]   (grid 4 x 256)
__global__ __launch_bounds__(256)
void s_reduce_kernel(float* __restrict__ ws) {
    const int d = blockIdx.x * 256 + threadIdx.x;
    float s = 0.0f;
    #pragma unroll 8
    for (int b = 0; b < NA_BLOCKS; ++b)
        s += ws[OFF_PART + (size_t)b * DDIM + d];
    ws[OFF_S + d] = s;
}

// Kernel C: one wave per pair (i, i+B): pos/neg -> softplus contributions
__global__ __launch_bounds__(NC_THREADS)
void img_kernel(const float* __restrict__ img, float* __restrict__ ws) {
    __shared__ float ls[NC_THREADS / 64];
    const int tid  = threadIdx.x;
    const int lane = tid & 63;
    const int wave = tid >> 6;
    const int pair = blockIdx.x * (NC_THREADS / 64) + wave;   // [0, BATCH)

    const float4* ap = reinterpret_cast<const float4*>(img + (size_t)pair * DDIM);
    const float4* bp = reinterpret_cast<const float4*>(img + (size_t)(pair + BATCH) * DDIM);
    const float4* sp = reinterpret_cast<const float4*>(ws + OFF_S);

    float ssqa = 0.f, ssqb = 0.f, dab = 0.f, das = 0.f, dbs = 0.f;

    #pragma unroll
    for (int c = 0; c < 4; ++c) {
        float4 va = ap[c * 64 + lane];
        float4 vb = bp[c * 64 + lane];
        float4 vs = sp[c * 64 + lane];
        ssqa = fmaf(va.x, va.x, ssqa); ssqa = fmaf(va.y, va.y, ssqa);
        ssqa = fmaf(va.z, va.z, ssqa); ssqa = fmaf(va.w, va.w, ssqa);
        ssqb = fmaf(vb.x, vb.x, ssqb); ssqb = fmaf(vb.y, vb.y, ssqb);
        ssqb = fmaf(vb.z, vb.z, ssqb); ssqb = fmaf(vb.w, vb.w, ssqb);
        dab  = fmaf(va.x, vb.x, dab);  dab  = fmaf(va.y, vb.y, dab);
        dab  = fmaf(va.z, vb.z, dab);  dab  = fmaf(va.w, vb.w, dab);
        das  = fmaf(va.x, vs.x, das);  das  = fmaf(va.y, vs.y, das);
        das  = fmaf(va.z, vs.z, das);  das  = fmaf(va.w, vs.w, das);
        dbs  = fmaf(vb.x, vs.x, dbs);  dbs  = fmaf(vb.y, vs.y, dbs);
        dbs  = fmaf(vb.z, vs.z, dbs);  dbs  = fmaf(vb.w, vs.w, dbs);
    }

    ssqa = wave_sum(ssqa);
    ssqb = wave_sum(ssqb);
    dab  = wave_sum(dab);
    das  = wave_sum(das);
    dbs  = wave_sum(dbs);

    if (lane == 0) {
        float ia  = 1.0f / fmaxf(sqrtf(ssqa), EPSN);
        float ib  = 1.0f / fmaxf(sqrtf(ssqb), EPSN);
        float pos = dab * ia * ib * TEMP_INV;      // shared by rows i and i+B
        float na  = das * ia * TEMP_INV;           // neg for row i
        float nb  = dbs * ib * TEMP_INV;           // neg for row i+B
        ls[wave] = softplus_stable(na - pos) + softplus_stable(nb - pos);
    }
    __syncthreads();
    if (tid == 0)
        ws[OFF_LP + blockIdx.x] = ls[0] + ls[1] + ls[2] + ls[3];
}

// Kernel D: final scalar = mean over 2B rows
__global__ __launch_bounds__(256)
void final_kernel(const float* __restrict__ ws, float* __restrict__ out) {
    __shared__ float ls[4];
    const int tid  = threadIdx.x;
    const int lane = tid & 63;
    const int wave = tid >> 6;
    float v = ws[OFF_LP + tid] + ws[OFF_LP + 256 + tid];
    v = wave_sum(v);
    if (lane == 0) ls[wave] = v;
    __syncthreads();
    if (tid == 0)
        out[0] = (ls[0] + ls[1] + ls[2] + ls[3]) * (1.0f / (2.0f * BATCH));
}

extern "C" void kernel_launch(void* const* d_in, const int* in_sizes, int n_in,
                              void* d_out, int out_size, void* d_ws, size_t ws_size,
                              hipStream_t stream) {
    const float* img = (const float*)d_in[0];   // [2B, D] fp32
    const float* mb  = (const float*)d_in[1];   // [M, D]  fp32
    float* out = (float*)d_out;
    float* ws  = (float*)d_ws;

    hipLaunchKernelGGL(mb_sum_kernel,   dim3(NA_BLOCKS), dim3(NA_THREADS), 0, stream, mb, ws);
    hipLaunchKernelGGL(s_reduce_kernel, dim3(4),         dim3(256),        0, stream, ws);
    hipLaunchKernelGGL(img_kernel,      dim3(NC_BLOCKS), dim3(NC_THREADS), 0, stream, img, ws);
    hipLaunchKernelGGL(final_kernel,    dim3(1),         dim3(256),        0, stream, ws, out);
}

// Round 3
// 30.697 us; speedup vs baseline: 1.8095x; 1.8095x over previous
//
#include <hip/hip_runtime.h>
#include <math.h>

// Problem constants (match reference)
#define DDIM   1024
#define BATCH  2048        // B; image_features has 2*B rows
#define MROWS  16384
#define TEMP_INV 10.0f     // 1/0.1
#define EPSN   1e-8f

// Kernel A geometry: 2048 blocks x 256 threads (4 waves), 8 rows/block, 2 rows/wave
#define NA_BLOCKS 2048
#define NA_THREADS 256
// Kernel C geometry
#define NC_BLOCKS 512
#define NC_THREADS 256     // 4 waves/block -> 2048 waves = B pairs

// ws layout in float4 units for the big arrays
#define OFF_PART4 0                         // [2048][256] float4 partials (8 MB)
#define OFF_P24   (NA_BLOCKS * 256)         // [16][256] float4 stage-2
#define OFF_S4    (OFF_P24 + 16 * 256)      // [256] float4 final s
// float-unit offset for loss partials
#define OFF_LP    ((OFF_S4 + 256) * 4)      // NC_BLOCKS floats

__device__ __forceinline__ float wave_sum(float v) {
    v += __shfl_xor(v, 32);
    v += __shfl_xor(v, 16);
    v += __shfl_xor(v, 8);
    v += __shfl_xor(v, 4);
    v += __shfl_xor(v, 2);
    v += __shfl_xor(v, 1);
    return v;
}

__device__ __forceinline__ float softplus_stable(float d) {
    return fmaxf(d, 0.0f) + log1pf(expf(-fabsf(d)));
}

// Kernel A: partial[block][d] = sum over the block's 8 rows of row/||row||.
// Full occupancy (8 blocks/CU), no atomics, one coalesced float4 write/thread.
__global__ __launch_bounds__(NA_THREADS, 6)
void mb_sum_kernel(const float* __restrict__ mb, float* __restrict__ ws) {
    __shared__ float4 lds4[4][256];
    const int tid  = threadIdx.x;
    const int lane = tid & 63;
    const int wave = tid >> 6;
    const int rbase = blockIdx.x * 8;

    float4 a0 = {0,0,0,0}, a1 = {0,0,0,0}, a2 = {0,0,0,0}, a3 = {0,0,0,0};

    #pragma unroll
    for (int k = 0; k < 2; ++k) {
        const int row = rbase + k * 4 + wave;
        const float4* rp = reinterpret_cast<const float4*>(mb + (size_t)row * DDIM);
        float4 v0 = rp[lane];
        float4 v1 = rp[64 + lane];
        float4 v2 = rp[128 + lane];
        float4 v3 = rp[192 + lane];

        float ssq = v0.x*v0.x + v0.y*v0.y + v0.z*v0.z + v0.w*v0.w
                  + v1.x*v1.x + v1.y*v1.y + v1.z*v1.z + v1.w*v1.w
                  + v2.x*v2.x + v2.y*v2.y + v2.z*v2.z + v2.w*v2.w
                  + v3.x*v3.x + v3.y*v3.y + v3.z*v3.z + v3.w*v3.w;
        ssq = wave_sum(ssq);
        float inv = 1.0f / fmaxf(sqrtf(ssq), EPSN);

        a0.x += v0.x*inv; a0.y += v0.y*inv; a0.z += v0.z*inv; a0.w += v0.w*inv;
        a1.x += v1.x*inv; a1.y += v1.y*inv; a1.z += v1.z*inv; a1.w += v1.w*inv;
        a2.x += v2.x*inv; a2.y += v2.y*inv; a2.z += v2.z*inv; a2.w += v2.w*inv;
        a3.x += v3.x*inv; a3.y += v3.y*inv; a3.z += v3.z*inv; a3.w += v3.w*inv;
    }

    // wave-local accumulators -> LDS tile [wave][float4 index of d]
    lds4[wave][lane]       = a0;
    lds4[wave][64 + lane]  = a1;
    lds4[wave][128 + lane] = a2;
    lds4[wave][192 + lane] = a3;
    __syncthreads();

    float4 t0 = lds4[0][tid], t1 = lds4[1][tid], t2 = lds4[2][tid], t3 = lds4[3][tid];
    float4 t;
    t.x = t0.x + t1.x + t2.x + t3.x;
    t.y = t0.y + t1.y + t2.y + t3.y;
    t.z = t0.z + t1.z + t2.z + t3.z;
    t.w = t0.w + t1.w + t2.w + t3.w;

    reinterpret_cast<float4*>(ws)[OFF_PART4 + (size_t)blockIdx.x * 256 + tid] = t;
}

// Kernel B1: stage-2 partials. grid (4,16): bx = d-group (64 float4), by = 128-row chunk.
__global__ __launch_bounds__(256)
void reduce1_kernel(float* __restrict__ ws) {
    const float4* part = reinterpret_cast<const float4*>(ws);
    const int col = threadIdx.x & 63;
    const int sub = threadIdx.x >> 6;
    const int c4  = blockIdx.x * 64 + col;
    const int by  = blockIdx.y;

    float4 a = {0,0,0,0};
    #pragma unroll 8
    for (int k = 0; k < 32; ++k) {
        const int r = by * 128 + k * 4 + sub;
        float4 v = part[(size_t)r * 256 + c4];
        a.x += v.x; a.y += v.y; a.z += v.z; a.w += v.w;
    }

    __shared__ float4 lds[4][64];
    lds[sub][col] = a;
    __syncthreads();
    if (sub == 0) {
        float4 u0 = lds[0][col], u1 = lds[1][col], u2 = lds[2][col], u3 = lds[3][col];
        float4 t;
        t.x = u0.x + u1.x + u2.x + u3.x;
        t.y = u0.y + u1.y + u2.y + u3.y;
        t.z = u0.z + u1.z + u2.z + u3.z;
        t.w = u0.w + u1.w + u2.w + u3.w;
        reinterpret_cast<float4*>(ws)[OFF_P24 + (size_t)by * 256 + c4] = t;
    }
}

// Kernel B2: s[d] = sum of 16 stage-2 rows. 1 block x 256 threads.
__global__ __launch_bounds__(256)
void reduce2_kernel(float* __restrict__ ws) {
    const float4* p2 = reinterpret_cast<const float4*>(ws) + OFF_P24;
    const int tid = threadIdx.x;
    float4 a = {0,0,0,0};
    #pragma unroll
    for (int j = 0; j < 16; ++j) {
        float4 v = p2[(size_t)j * 256 + tid];
        a.x += v.x; a.y += v.y; a.z += v.z; a.w += v.w;
    }
    reinterpret_cast<float4*>(ws)[OFF_S4 + tid] = a;
}

// Kernel C: one wave per pair (i, i+B): pos/neg -> softplus contributions
__global__ __launch_bounds__(NC_THREADS)
void img_kernel(const float* __restrict__ img, float* __restrict__ ws) {
    __shared__ float ls[NC_THREADS / 64];
    const int tid  = threadIdx.x;
    const int lane = tid & 63;
    const int wave = tid >> 6;
    const int pair = blockIdx.x * (NC_THREADS / 64) + wave;   // [0, BATCH)

    const float4* ap = reinterpret_cast<const float4*>(img + (size_t)pair * DDIM);
    const float4* bp = reinterpret_cast<const float4*>(img + (size_t)(pair + BATCH) * DDIM);
    const float4* sp = reinterpret_cast<const float4*>(ws) + OFF_S4;

    float ssqa = 0.f, ssqb = 0.f, dab = 0.f, das = 0.f, dbs = 0.f;

    #pragma unroll
    for (int c = 0; c < 4; ++c) {
        float4 va = ap[c * 64 + lane];
        float4 vb = bp[c * 64 + lane];
        float4 vs = sp[c * 64 + lane];
        ssqa = fmaf(va.x, va.x, ssqa); ssqa = fmaf(va.y, va.y, ssqa);
        ssqa = fmaf(va.z, va.z, ssqa); ssqa = fmaf(va.w, va.w, ssqa);
        ssqb = fmaf(vb.x, vb.x, ssqb); ssqb = fmaf(vb.y, vb.y, ssqb);
        ssqb = fmaf(vb.z, vb.z, ssqb); ssqb = fmaf(vb.w, vb.w, ssqb);
        dab  = fmaf(va.x, vb.x, dab);  dab  = fmaf(va.y, vb.y, dab);
        dab  = fmaf(va.z, vb.z, dab);  dab  = fmaf(va.w, vb.w, dab);
        das  = fmaf(va.x, vs.x, das);  das  = fmaf(va.y, vs.y, das);
        das  = fmaf(va.z, vs.z, das);  das  = fmaf(va.w, vs.w, das);
        dbs  = fmaf(vb.x, vs.x, dbs);  dbs  = fmaf(vb.y, vs.y, dbs);
        dbs  = fmaf(vb.z, vs.z, dbs);  dbs  = fmaf(vb.w, vs.w, dbs);
    }

    ssqa = wave_sum(ssqa);
    ssqb = wave_sum(ssqb);
    dab  = wave_sum(dab);
    das  = wave_sum(das);
    dbs  = wave_sum(dbs);

    if (lane == 0) {
        float ia  = 1.0f / fmaxf(sqrtf(ssqa), EPSN);
        float ib  = 1.0f / fmaxf(sqrtf(ssqb), EPSN);
        float pos = dab * ia * ib * TEMP_INV;      // shared by rows i and i+B
        float na  = das * ia * TEMP_INV;           // neg for row i
        float nb  = dbs * ib * TEMP_INV;           // neg for row i+B
        ls[wave] = softplus_stable(na - pos) + softplus_stable(nb - pos);
    }
    __syncthreads();
    if (tid == 0)
        ws[OFF_LP + blockIdx.x] = ls[0] + ls[1] + ls[2] + ls[3];
}

// Kernel D: final scalar = mean over 2B rows
__global__ __launch_bounds__(256)
void final_kernel(const float* __restrict__ ws, float* __restrict__ out) {
    __shared__ float ls[4];
    const int tid  = threadIdx.x;
    const int lane = tid & 63;
    const int wave = tid >> 6;
    float v = ws[OFF_LP + tid] + ws[OFF_LP + 256 + tid];
    v = wave_sum(v);
    if (lane == 0) ls[wave] = v;
    __syncthreads();
    if (tid == 0)
        out[0] = (ls[0] + ls[1] + ls[2] + ls[3]) * (1.0f / (2.0f * BATCH));
}

extern "C" void kernel_launch(void* const* d_in, const int* in_sizes, int n_in,
                              void* d_out, int out_size, void* d_ws, size_t ws_size,
                              hipStream_t stream) {
    const float* img = (const float*)d_in[0];   // [2B, D] fp32
    const float* mb  = (const float*)d_in[1];   // [M, D]  fp32
    float* out = (float*)d_out;
    float* ws  = (float*)d_ws;

    hipLaunchKernelGGL(mb_sum_kernel,  dim3(NA_BLOCKS), dim3(NA_THREADS), 0, stream, mb, ws);
    hipLaunchKernelGGL(reduce1_kernel, dim3(4, 16),     dim3(256),        0, stream, ws);
    hipLaunchKernelGGL(reduce2_kernel, dim3(1),         dim3(256),        0, stream, ws);
    hipLaunchKernelGGL(img_kernel,     dim3(NC_BLOCKS), dim3(NC_THREADS), 0, stream, img, ws);
    hipLaunchKernelGGL(final_kernel,   dim3(1),         dim3(256),        0, stream, ws, out);
}